// Round 13
// baseline (2945.448 us; speedup 1.0000x reference)
//
#include <hip/hip_runtime.h>
#include <cstdint>
#include <cstddef>

#define B_ 4096
#define L_ 12
#define A_ 768
#define F_ 4096
#define NTRI 78

typedef __bf16 bf16x8 __attribute__((ext_vector_type(8)));
typedef float f32x4 __attribute__((ext_vector_type(4)));
typedef unsigned short u16x4 __attribute__((ext_vector_type(4)));
typedef unsigned short u16x8 __attribute__((ext_vector_type(8)));

__device__ __forceinline__ unsigned short f32_to_bf16(float f) {
  unsigned int u = __float_as_uint(f);
  u += 0x7fffu + ((u >> 16) & 1u);   // round-to-nearest-even
  return (unsigned short)(u >> 16);
}

__device__ __forceinline__ void gload_lds16(const void* g, void* l) {
  __builtin_amdgcn_global_load_lds(
      (const __attribute__((address_space(1))) void*)g,
      (__attribute__((address_space(3))) void*)l,
      16, 0, 0);
}

// ---------------------------------------------------------------------------
// prep_sx: sx[l][b][a] = (x[b][l][a] - mean[l][a]) / std[l][a]  (bf16)
// ---------------------------------------------------------------------------
__global__ __launch_bounds__(256) void prep_sx(
    const float* __restrict__ x, const float* __restrict__ mean,
    const float* __restrict__ stdv, unsigned short* __restrict__ sx) {
  size_t i4 = (size_t)blockIdx.x * 256 + threadIdx.x;
  size_t e = i4 * 4;
  if (e >= (size_t)B_ * L_ * A_) return;
  unsigned int a = (unsigned int)(e % A_);
  unsigned int t = (unsigned int)(e / A_);
  unsigned int b = t / L_;
  unsigned int l = t % L_;
  float4 xv = *(const float4*)(x + e);
  float4 mv = *(const float4*)(mean + (size_t)l * A_ + a);
  float4 sv = *(const float4*)(stdv + (size_t)l * A_ + a);
  u16x4 o;
  o.x = f32_to_bf16((xv.x - mv.x) / sv.x);
  o.y = f32_to_bf16((xv.y - mv.y) / sv.y);
  o.z = f32_to_bf16((xv.z - mv.z) / sv.z);
  o.w = f32_to_bf16((xv.w - mv.w) / sv.w);
  *(u16x4*)(sx + ((size_t)l * B_ + b) * A_ + a) = o;
}

// ---------------------------------------------------------------------------
// transpose_cvt64: per z-slice (R x C f32, row-major) -> out (C x R bf16).
// ---------------------------------------------------------------------------
__global__ __launch_bounds__(256) void transpose_cvt64(
    const float* __restrict__ in, unsigned short* __restrict__ out,
    int R, int C) {
  __shared__ float tile[64][65];
  const float* inz = in + (size_t)blockIdx.z * R * C;
  unsigned short* outz = out + (size_t)blockIdx.z * R * C;
  const int c0 = blockIdx.x * 64, r0 = blockIdx.y * 64;
  const int t = threadIdx.x;
  {
    const int c = (t & 15) * 4;
    const int rb = t >> 4;
#pragma unroll
    for (int q = 0; q < 4; ++q) {
      const int r = rb + q * 16;
      float4 v = *(const float4*)(inz + (size_t)(r0 + r) * C + (c0 + c));
      tile[r][c] = v.x; tile[r][c + 1] = v.y;
      tile[r][c + 2] = v.z; tile[r][c + 3] = v.w;
    }
  }
  __syncthreads();
  {
    const int c = t >> 2;
    const int rb = (t & 3) * 16;
#pragma unroll
    for (int h = 0; h < 2; ++h) {
      u16x8 o;
#pragma unroll
      for (int j = 0; j < 8; ++j) o[j] = f32_to_bf16(tile[rb + h * 8 + j][c]);
      *(u16x8*)(outz + (size_t)(c0 + c) * R + (r0 + rb + h * 8)) = o;
    }
  }
}

// ---------------------------------------------------------------------------
// 8-wave 256x256-tile GEMM core (unchanged, used by enc_fused): 16x16x32,
// BK=64, ring-2 k-half staging, counted vmcnt(4), r7-verified swizzle.
// ---------------------------------------------------------------------------
template <class KOffA, class KOffB>
__device__ __forceinline__ void gemm_core64(
    int KT, char* AS, char* BS,
    const char* gA0s, const char* gB0s,
    int ldA, int ldB,
    int w, int wr, int wc, int lane,
    KOffA koffA, KOffB koffB, f32x4 (&acc)[8][4]) {
  const int g = lane >> 4;
  const int fr = lane & 15;
  const uint32_t ssr = (uint32_t)((g ^ ((fr >> 1) & 3)) * 16);
  const uint32_t aBase = (uint32_t)(wr * 128 + fr) * 64 + ssr;
  const uint32_t bBase = (uint32_t)(wc * 64 + fr) * 64 + ssr;

  auto stageA = [&](int kt, int h) {
    const uint32_t off = koffA(kt) + (uint32_t)(h * 64);
    char* d = AS + ((kt & 1) << 15) + (h << 14) + (w << 10);
    gload_lds16(gA0s + off, d);
    gload_lds16(gA0s + off + 128u * (uint32_t)ldA, d + 8192);
  };
  auto stageB = [&](int kt, int h) {
    const uint32_t off = koffB(kt) + (uint32_t)(h * 64);
    char* d = BS + ((kt & 1) << 15) + (h << 14) + (w << 10);
    gload_lds16(gB0s + off, d);
    gload_lds16(gB0s + off + 128u * (uint32_t)ldB, d + 8192);
  };

  stageA(0, 0); stageB(0, 0); stageA(0, 1); stageB(0, 1);
  asm volatile("s_waitcnt vmcnt(4)" ::: "memory");
  __builtin_amdgcn_s_barrier();

  bf16x8 bk[4], aA[4], aB[4];
  for (int kt = 0; kt < KT; ++kt) {
    const char* Ab = AS + ((kt & 1) << 15);
    const char* Bb = BS + ((kt & 1) << 15);
    const bool more = (kt + 1 < KT);
#pragma unroll
    for (int ni = 0; ni < 4; ++ni)
      bk[ni] = *(const bf16x8*)(Bb + bBase + ni * 1024);
#pragma unroll
    for (int mi = 0; mi < 4; ++mi)
      aA[mi] = *(const bf16x8*)(Ab + aBase + mi * 1024);
    if (more) stageA(kt + 1, 0);
    asm volatile("" ::: "memory");
    __builtin_amdgcn_s_barrier();
    __builtin_amdgcn_s_setprio(1);
#pragma unroll
    for (int mi = 0; mi < 4; ++mi)
#pragma unroll
      for (int ni = 0; ni < 4; ++ni)
        acc[mi][ni] = __builtin_amdgcn_mfma_f32_16x16x32_bf16(
            aA[mi], bk[ni], acc[mi][ni], 0, 0, 0);
    __builtin_amdgcn_s_setprio(0);
    asm volatile("" ::: "memory");
    __builtin_amdgcn_s_barrier();
#pragma unroll
    for (int mi = 0; mi < 4; ++mi)
      aB[mi] = *(const bf16x8*)(Ab + aBase + (4 + mi) * 1024);
    if (more) stageB(kt + 1, 0);
    asm volatile("" ::: "memory");
    __builtin_amdgcn_s_barrier();
    __builtin_amdgcn_s_setprio(1);
#pragma unroll
    for (int mi = 0; mi < 4; ++mi)
#pragma unroll
      for (int ni = 0; ni < 4; ++ni)
        acc[mi + 4][ni] = __builtin_amdgcn_mfma_f32_16x16x32_bf16(
            aB[mi], bk[ni], acc[mi + 4][ni], 0, 0, 0);
    __builtin_amdgcn_s_setprio(0);
    if (more) { asm volatile("s_waitcnt vmcnt(4)" ::: "memory"); }
    else      { asm volatile("s_waitcnt vmcnt(0)" ::: "memory"); }
    __builtin_amdgcn_s_barrier();
#pragma unroll
    for (int ni = 0; ni < 4; ++ni)
      bk[ni] = *(const bf16x8*)(Bb + 16384 + bBase + ni * 1024);
#pragma unroll
    for (int mi = 0; mi < 4; ++mi)
      aA[mi] = *(const bf16x8*)(Ab + 16384 + aBase + mi * 1024);
    if (more) stageA(kt + 1, 1);
    asm volatile("" ::: "memory");
    __builtin_amdgcn_s_barrier();
    __builtin_amdgcn_s_setprio(1);
#pragma unroll
    for (int mi = 0; mi < 4; ++mi)
#pragma unroll
      for (int ni = 0; ni < 4; ++ni)
        acc[mi][ni] = __builtin_amdgcn_mfma_f32_16x16x32_bf16(
            aA[mi], bk[ni], acc[mi][ni], 0, 0, 0);
    __builtin_amdgcn_s_setprio(0);
    asm volatile("" ::: "memory");
    __builtin_amdgcn_s_barrier();
#pragma unroll
    for (int mi = 0; mi < 4; ++mi)
      aB[mi] = *(const bf16x8*)(Ab + 16384 + aBase + (4 + mi) * 1024);
    if (more) stageB(kt + 1, 1);
    asm volatile("" ::: "memory");
    __builtin_amdgcn_s_barrier();
    __builtin_amdgcn_s_setprio(1);
#pragma unroll
    for (int mi = 0; mi < 4; ++mi)
#pragma unroll
      for (int ni = 0; ni < 4; ++ni)
        acc[mi + 4][ni] = __builtin_amdgcn_mfma_f32_16x16x32_bf16(
            aB[mi], bk[ni], acc[mi + 4][ni], 0, 0, 0);
    __builtin_amdgcn_s_setprio(0);
    if (more) { asm volatile("s_waitcnt vmcnt(4)" ::: "memory"); }
    __builtin_amdgcn_s_barrier();
  }
}

// ---------------------------------------------------------------------------
// Fused encoder + partial Wdec transpose (r12, unchanged).
// ---------------------------------------------------------------------------
__global__ __launch_bounds__(512, 2) void enc_fused(
    const unsigned short* __restrict__ sxT,   // (L,B,A)
    const unsigned short* __restrict__ wT,    // (L,F,A)
    const float* __restrict__ theta,          // (L,F)
    float* __restrict__ enc_out,              // (B,L,F)
    unsigned short* __restrict__ act,         // (L,B,F)
    const float* __restrict__ wdec_in,        // (NTRI,F,A) f32
    unsigned short* __restrict__ wdecT_out)   // (NTRI,A,F) bf16
{
  extern __shared__ __align__(16) char lds[];
  const int bidx = blockIdx.x;
  const int grp = bidx / 17;
  const int rem = bidx - grp * 17;

  if (rem >= 8) {
    const int tr = grp * 9 + (rem - 8);     // 0..3455
    const int y = tr & 63;
    const int z = 24 + (tr >> 6);           // 24..77
    float (*tile)[65] = (float(*)[65])lds;
    const float* inz = wdec_in + (size_t)z * F_ * A_;
    unsigned short* outz = wdecT_out + (size_t)z * F_ * A_;
    const int r0 = y * 64;
    const int t = threadIdx.x;
    for (int xq = 0; xq < 12; ++xq) {
      const int c0 = xq * 64;
      {
        const int c = (t & 15) * 4;
        const int rb = t >> 4;
#pragma unroll
        for (int q = 0; q < 2; ++q) {
          const int r = rb + q * 32;
          float4 v = *(const float4*)(inz + (size_t)(r0 + r) * A_ + (c0 + c));
          tile[r][c] = v.x; tile[r][c + 1] = v.y;
          tile[r][c + 2] = v.z; tile[r][c + 3] = v.w;
        }
      }
      __syncthreads();
      {
        const int c = t >> 3;
        const int rb8 = (t & 7) * 8;
        u16x8 o;
#pragma unroll
        for (int j = 0; j < 8; ++j) o[j] = f32_to_bf16(tile[rb8 + j][c]);
        *(u16x8*)(outz + (size_t)(c0 + c) * F_ + (r0 + rb8)) = o;
      }
      __syncthreads();
    }
    return;
  }

  char* AS = lds;
  char* BS = lds + 65536;
  const int e = grp * 8 + rem;
  const int wg = (e & 7) * 384 + (e >> 3);
  const int l = wg >> 8;
  const int blk = wg & 255;
  const int m0 = (blk & 15) * 256;
  const int n0 = (blk >> 4) * 256;
  const int tid = threadIdx.x;
  const int w = tid >> 6, lane = tid & 63;
  const int wr = w >> 2, wc = w & 3;
  const int srowS = w * 16 + (lane >> 2);
  const int chnkS = ((lane & 3) ^ ((lane >> 3) & 3)) * 16;

  const char* gA0s = (const char*)sxT +
      ((size_t)l * B_ + m0 + srowS) * (A_ * 2) + chnkS;
  const char* gB0s = (const char*)wT +
      ((size_t)l * F_ + n0 + srowS) * (A_ * 2) + chnkS;

  f32x4 acc[8][4] = {};
  auto koffA = [](int kt) { return (uint32_t)kt * 128u; };
  auto koffB = [](int kt) { return (uint32_t)kt * 128u; };
  gemm_core64(A_ / 64, AS, BS, gA0s, gB0s, A_ * 2, A_ * 2, w, wr, wc, lane,
              koffA, koffB, acc);

  const int g = lane >> 4, fr = lane & 15;
#pragma unroll
  for (int ni = 0; ni < 4; ++ni) {
    const int gcol = n0 + wc * 64 + ni * 16 + fr;
    const float th = theta[(size_t)l * F_ + gcol];
#pragma unroll
    for (int mi = 0; mi < 8; ++mi) {
      const int growb = m0 + wr * 128 + mi * 16 + g * 4;
#pragma unroll
      for (int jj = 0; jj < 4; ++jj) {
        const float v = acc[mi][ni][jj];
        const size_t grow = (size_t)(growb + jj);
        enc_out[(grow * L_ + l) * F_ + gcol] = v;
        act[((size_t)l * B_ + grow) * F_ + gcol] =
            (v > th) ? f32_to_bf16(v) : (unsigned short)0;
      }
    }
  }
}

// ---------------------------------------------------------------------------
// NEW decoder: 12-wave (768-thread) 256x192 tile, 3 waves/SIMD.
// Waves 4M x 3N, per-wave output 64x64 -> acc = 64 VGPR (fits 170-cap for
// 3 waves/SIMD). BK=32, ring-4 LDS (A 4x16KB + B 4x12KB = 112 KiB),
// prefetch distance 3, ONE barrier per K-tile, counted role-split vmcnt:
//   waves 0-7  stage A (2 gloads/tile) -> vmcnt(4) keeps 2 tiles in flight
//   waves 8-11 stage B (3 gloads/tile) -> vmcnt(6)
// Swizzle: r7-verified (store chunk = (lane&3)^((lane>>3)&3), read chunk =
// g^((fr>>1)&3)); all staging row bases are multiples of 16 so the store
// formula stays exact.
// Race ledger: stage(kt+3) targets slot (kt-1)&3; every wave's reads of tile
// kt-1 precede its end-of-(kt-1) barrier, which precedes any stage of kt+3.
// Publish: end-of-kt counted vmcnt + barrier proves tile kt+1 landed.
// Grid 768 = 12 layers x (16m x 4n), heavy layers first; exactly 3
// blocks/CU-round.
// ---------------------------------------------------------------------------
__global__ __launch_bounds__(768) void dec_gemm12(
    const unsigned short* __restrict__ act,    // (L,B,F)
    const unsigned short* __restrict__ wdecT,  // (NTRI,A,F)
    float* __restrict__ logits)                // (B,L,A)
{
  extern __shared__ __align__(16) char lds[];
  char* AS = lds;            // 4 slots x 16 KiB
  char* BS = lds + 65536;    // 4 slots x 12 KiB
  const int b = blockIdx.x;
  const int z = b >> 6;            // 0..11, heavy first
  const int blk = b & 63;
  const int i = 11 - z;
  const int m0 = (blk & 15) * 256;
  const int n0 = (blk >> 4) * 192; // {0,192,384,576}
  const int triBase = i * (i + 1) / 2;
  const int KT = (i + 1) * 128;    // BK=32 tiles
  const int tid = threadIdx.x;
  const int w = tid >> 6, lane = tid & 63;
  const int wr = w & 3;            // 0..3 (M)
  const int wc = w >> 2;           // 0..2 (N)
  const int g = lane >> 4, fr = lane & 15;
  const uint32_t ssr = (uint32_t)((g ^ ((fr >> 1) & 3)) * 16);
  const uint32_t aBase = (uint32_t)(wr * 64 + fr) * 64 + ssr;
  const uint32_t bBase = (uint32_t)(wc * 64 + fr) * 64 + ssr;

  const bool isA = (w < 8);
  const int chnkS = ((lane & 3) ^ ((lane >> 3) & 3)) * 16;
  const int srowS = isA ? (w * 32 + (lane >> 2))
                        : ((w - 8) * 48 + (lane >> 2));
  const char* gS = isA
      ? (const char*)act + (size_t)(m0 + srowS) * (F_ * 2) + chnkS
      : (const char*)wdecT +
            ((size_t)triBase * A_ + n0 + srowS) * (F_ * 2) + chnkS;
  const size_t layerStride = isA ? (size_t)B_ * F_ * 2 : (size_t)A_ * F_ * 2;
  char* sBase = isA ? AS : BS;
  const int slotSz = isA ? 16384 : 12288;
  const int cOff = isA ? (w << 11) : ((w - 8) * 3072);
  const int nq = isA ? 2 : 3;

  auto stage = [&](int kt) {
    const size_t off =
        (size_t)(kt >> 7) * layerStride + (size_t)((kt & 127) * 64);
    char* d = sBase + (kt & 3) * slotSz + cOff;
    for (int q = 0; q < nq; ++q)
      gload_lds16(gS + off + (size_t)q * (16 * F_ * 2), d + q * 1024);
  };

  f32x4 acc[4][4] = {};

  // prologue: tiles 0,1,2 staged; counted wait -> tile 0 landed.
  stage(0); stage(1); stage(2);
  if (isA) { asm volatile("s_waitcnt vmcnt(4)" ::: "memory"); }
  else     { asm volatile("s_waitcnt vmcnt(6)" ::: "memory"); }
  __builtin_amdgcn_s_barrier();

  for (int kt = 0; kt < KT; ++kt) {
    const char* Ab = AS + (kt & 3) * 16384;
    const char* Bb = BS + (kt & 3) * 12288;
    bf16x8 ak[4], bk[4];
#pragma unroll
    for (int ni = 0; ni < 4; ++ni)
      bk[ni] = *(const bf16x8*)(Bb + bBase + ni * 1024);
#pragma unroll
    for (int mi = 0; mi < 4; ++mi)
      ak[mi] = *(const bf16x8*)(Ab + aBase + mi * 1024);
    if (kt + 3 < KT) stage(kt + 3);
    __builtin_amdgcn_s_setprio(1);
#pragma unroll
    for (int mi = 0; mi < 4; ++mi)
#pragma unroll
      for (int ni = 0; ni < 4; ++ni)
        acc[mi][ni] = __builtin_amdgcn_mfma_f32_16x16x32_bf16(
            ak[mi], bk[ni], acc[mi][ni], 0, 0, 0);
    __builtin_amdgcn_s_setprio(0);
    if (kt + 3 < KT) {
      if (isA) { asm volatile("s_waitcnt vmcnt(4)" ::: "memory"); }
      else     { asm volatile("s_waitcnt vmcnt(6)" ::: "memory"); }
    } else if (kt + 2 < KT) {
      if (isA) { asm volatile("s_waitcnt vmcnt(2)" ::: "memory"); }
      else     { asm volatile("s_waitcnt vmcnt(3)" ::: "memory"); }
    } else if (kt + 1 < KT) {
      asm volatile("s_waitcnt vmcnt(0)" ::: "memory");
    }
    asm volatile("" ::: "memory");
    __builtin_amdgcn_s_barrier();
  }

#pragma unroll
  for (int mi = 0; mi < 4; ++mi) {
    const int growb = m0 + wr * 64 + mi * 16 + g * 4;
#pragma unroll
    for (int ni = 0; ni < 4; ++ni) {
      const int gcol = n0 + wc * 64 + ni * 16 + fr;
#pragma unroll
      for (int jj = 0; jj < 4; ++jj)
        logits[((size_t)(growb + jj) * L_ + i) * A_ + gcol] = acc[mi][ni][jj];
    }
  }
}

// ---------------------------------------------------------------------------
extern "C" void kernel_launch(void* const* d_in, const int* in_sizes, int n_in,
                              void* d_out, int out_size, void* d_ws,
                              size_t ws_size, hipStream_t stream) {
  (void)in_sizes; (void)n_in; (void)out_size; (void)ws_size;
  const float* x = (const float*)d_in[0];
  const float* mean = (const float*)d_in[1];
  const float* stdv = (const float*)d_in[2];
  const float* Wenc = (const float*)d_in[3];
  const float* theta = (const float*)d_in[4];
  const float* Wdec = (const float*)d_in[5];

  float* logits = (float*)d_out;
  float* enc = (float*)d_out + (size_t)B_ * L_ * A_;

  char* ws = (char*)d_ws;
  const size_t actBytes = (size_t)L_ * B_ * F_ * 2;      // 402.7 MB
  const size_t sxBytes = (size_t)L_ * B_ * A_ * 2;       // 75.5 MB
  unsigned short* act = (unsigned short*)ws;
  unsigned short* sx = (unsigned short*)(ws + actBytes);
  unsigned short* wencT = (unsigned short*)(ws + actBytes + sxBytes);
  // wdecT aliases over sx+wencT; tris >=24 lie beyond them (safe during enc).
  unsigned short* wdecT = (unsigned short*)(ws + actBytes);

  hipFuncSetAttribute((const void*)enc_fused,
                      hipFuncAttributeMaxDynamicSharedMemorySize, 131072);
  hipFuncSetAttribute((const void*)dec_gemm12,
                      hipFuncAttributeMaxDynamicSharedMemorySize, 114688);

  prep_sx<<<(B_ * L_ * A_ / 4 + 255) / 256, 256, 0, stream>>>(x, mean, stdv, sx);
  transpose_cvt64<<<dim3(F_ / 64, A_ / 64, L_), 256, 0, stream>>>(
      Wenc, wencT, A_, F_);
  enc_fused<<<6528, 512, 131072, stream>>>(sx, wencT, theta, enc, act,
                                           Wdec, wdecT);
  transpose_cvt64<<<dim3(A_ / 64, F_ / 64, 24), 256, 0, stream>>>(
      Wdec, wdecT, F_, A_);
  dec_gemm12<<<768, 768, 114688, stream>>>(act, wdecT, logits);
}

// Round 15
// 2728.159 us; speedup vs baseline: 1.0796x; 1.0796x over previous
//
#include <hip/hip_runtime.h>
#include <cstdint>
#include <cstddef>

#define B_ 4096
#define L_ 12
#define A_ 768
#define F_ 4096
#define NTRI 78

typedef __bf16 bf16x8 __attribute__((ext_vector_type(8)));
typedef float f32x4 __attribute__((ext_vector_type(4)));
typedef unsigned short u16x4 __attribute__((ext_vector_type(4)));
typedef unsigned short u16x8 __attribute__((ext_vector_type(8)));

__device__ __forceinline__ unsigned short f32_to_bf16(float f) {
  unsigned int u = __float_as_uint(f);
  u += 0x7fffu + ((u >> 16) & 1u);   // round-to-nearest-even
  return (unsigned short)(u >> 16);
}

__device__ __forceinline__ void gload_lds16(const void* g, void* l) {
  __builtin_amdgcn_global_load_lds(
      (const __attribute__((address_space(1))) void*)g,
      (__attribute__((address_space(3))) void*)l,
      16, 0, 0);
}

// ---------------------------------------------------------------------------
// prep_enc_inputs: two roles in one launch (both HBM-bound):
//   role 0 (blocks < 36864): sx[l][b][a] = (x[b][l][a]-mean)/std  (bf16)
//                            (36864 = B*L*A/4/256 — full coverage)
//   role 1 (blocks >= 36864): Wenc (L,A,F) -> wencT (L,F,A) 64x64-tile
// ---------------------------------------------------------------------------
__global__ __launch_bounds__(256) void prep_enc_inputs(
    const float* __restrict__ x, const float* __restrict__ mean,
    const float* __restrict__ stdv, unsigned short* __restrict__ sx,
    const float* __restrict__ wenc, unsigned short* __restrict__ wencT) {
  const int bid = blockIdx.x;
  if (bid < 36864) {
    size_t i4 = (size_t)bid * 256 + threadIdx.x;
    size_t e = i4 * 4;
    unsigned int a = (unsigned int)(e % A_);
    unsigned int t = (unsigned int)(e / A_);
    unsigned int b = t / L_;
    unsigned int l = t % L_;
    float4 xv = *(const float4*)(x + e);
    float4 mv = *(const float4*)(mean + (size_t)l * A_ + a);
    float4 sv = *(const float4*)(stdv + (size_t)l * A_ + a);
    u16x4 o;
    o.x = f32_to_bf16((xv.x - mv.x) / sv.x);
    o.y = f32_to_bf16((xv.y - mv.y) / sv.y);
    o.z = f32_to_bf16((xv.z - mv.z) / sv.z);
    o.w = f32_to_bf16((xv.w - mv.w) / sv.w);
    *(u16x4*)(sx + ((size_t)l * B_ + b) * A_ + a) = o;
    return;
  }
  // Wenc transpose role: per (l, ytile, xtile): in (A_ x F_) -> out (F_ x A_)
  __shared__ float tile[64][65];
  const int tr = bid - 36864;             // 0..9215
  const int xq = tr % 12;                 // A-dim tile (cols of out)
  const int rest = tr / 12;
  const int y = rest & 63;                // F-dim tile
  const int l = rest >> 6;                // 0..11
  const float* inz = wenc + (size_t)l * A_ * F_;
  unsigned short* outz = wencT + (size_t)l * F_ * A_;
  const int r0 = xq * 64;                 // row in Wenc = A-dim
  const int c0 = y * 64;                  // col in Wenc = F-dim
  const int t = threadIdx.x;
  {
    const int c = (t & 15) * 4;
    const int rb = t >> 4;
#pragma unroll
    for (int q = 0; q < 4; ++q) {
      const int r = rb + q * 16;
      float4 v = *(const float4*)(inz + (size_t)(r0 + r) * F_ + (c0 + c));
      tile[r][c] = v.x; tile[r][c + 1] = v.y;
      tile[r][c + 2] = v.z; tile[r][c + 3] = v.w;
    }
  }
  __syncthreads();
  {
    const int c = t >> 2;                 // 0..63 (F-dim within tile)
    const int rb = (t & 3) * 16;
#pragma unroll
    for (int h = 0; h < 2; ++h) {
      u16x8 o;
#pragma unroll
      for (int j = 0; j < 8; ++j) o[j] = f32_to_bf16(tile[rb + h * 8 + j][c]);
      *(u16x8*)(outz + (size_t)(c0 + c) * A_ + (r0 + rb + h * 8)) = o;
    }
  }
}

// ---------------------------------------------------------------------------
// transpose_cvt64: per z-slice (R x C f32, row-major) -> out (C x R bf16).
// Used for the Wdec tris 0..23 tail.
// ---------------------------------------------------------------------------
__global__ __launch_bounds__(256) void transpose_cvt64(
    const float* __restrict__ in, unsigned short* __restrict__ out,
    int R, int C) {
  __shared__ float tile[64][65];
  const float* inz = in + (size_t)blockIdx.z * R * C;
  unsigned short* outz = out + (size_t)blockIdx.z * R * C;
  const int c0 = blockIdx.x * 64, r0 = blockIdx.y * 64;
  const int t = threadIdx.x;
  {
    const int c = (t & 15) * 4;
    const int rb = t >> 4;
#pragma unroll
    for (int q = 0; q < 4; ++q) {
      const int r = rb + q * 16;
      float4 v = *(const float4*)(inz + (size_t)(r0 + r) * C + (c0 + c));
      tile[r][c] = v.x; tile[r][c + 1] = v.y;
      tile[r][c + 2] = v.z; tile[r][c + 3] = v.w;
    }
  }
  __syncthreads();
  {
    const int c = t >> 2;
    const int rb = (t & 3) * 16;
#pragma unroll
    for (int h = 0; h < 2; ++h) {
      u16x8 o;
#pragma unroll
      for (int j = 0; j < 8; ++j) o[j] = f32_to_bf16(tile[rb + h * 8 + j][c]);
      *(u16x8*)(outz + (size_t)(c0 + c) * R + (r0 + rb + h * 8)) = o;
    }
  }
}

// ---------------------------------------------------------------------------
// 8-wave 256x256-tile GEMM core (r11, best measured): 16x16x32, BK=64,
// ring-2 k-half staging, counted vmcnt(4), r7-verified 0-conflict swizzle.
// ---------------------------------------------------------------------------
template <class KOffA, class KOffB>
__device__ __forceinline__ void gemm_core64(
    int KT, char* AS, char* BS,
    const char* gA0s, const char* gB0s,
    int ldA, int ldB,
    int w, int wr, int wc, int lane,
    KOffA koffA, KOffB koffB, f32x4 (&acc)[8][4]) {
  const int g = lane >> 4;
  const int fr = lane & 15;
  const uint32_t ssr = (uint32_t)((g ^ ((fr >> 1) & 3)) * 16);
  const uint32_t aBase = (uint32_t)(wr * 128 + fr) * 64 + ssr;
  const uint32_t bBase = (uint32_t)(wc * 64 + fr) * 64 + ssr;

  auto stageA = [&](int kt, int h) {
    const uint32_t off = koffA(kt) + (uint32_t)(h * 64);
    char* d = AS + ((kt & 1) << 15) + (h << 14) + (w << 10);
    gload_lds16(gA0s + off, d);
    gload_lds16(gA0s + off + 128u * (uint32_t)ldA, d + 8192);
  };
  auto stageB = [&](int kt, int h) {
    const uint32_t off = koffB(kt) + (uint32_t)(h * 64);
    char* d = BS + ((kt & 1) << 15) + (h << 14) + (w << 10);
    gload_lds16(gB0s + off, d);
    gload_lds16(gB0s + off + 128u * (uint32_t)ldB, d + 8192);
  };

  stageA(0, 0); stageB(0, 0); stageA(0, 1); stageB(0, 1);
  asm volatile("s_waitcnt vmcnt(4)" ::: "memory");
  __builtin_amdgcn_s_barrier();

  bf16x8 bk[4], aA[4], aB[4];
  for (int kt = 0; kt < KT; ++kt) {
    const char* Ab = AS + ((kt & 1) << 15);
    const char* Bb = BS + ((kt & 1) << 15);
    const bool more = (kt + 1 < KT);
#pragma unroll
    for (int ni = 0; ni < 4; ++ni)
      bk[ni] = *(const bf16x8*)(Bb + bBase + ni * 1024);
#pragma unroll
    for (int mi = 0; mi < 4; ++mi)
      aA[mi] = *(const bf16x8*)(Ab + aBase + mi * 1024);
    if (more) stageA(kt + 1, 0);
    asm volatile("" ::: "memory");
    __builtin_amdgcn_s_barrier();
    __builtin_amdgcn_s_setprio(1);
#pragma unroll
    for (int mi = 0; mi < 4; ++mi)
#pragma unroll
      for (int ni = 0; ni < 4; ++ni)
        acc[mi][ni] = __builtin_amdgcn_mfma_f32_16x16x32_bf16(
            aA[mi], bk[ni], acc[mi][ni], 0, 0, 0);
    __builtin_amdgcn_s_setprio(0);
    asm volatile("" ::: "memory");
    __builtin_amdgcn_s_barrier();
#pragma unroll
    for (int mi = 0; mi < 4; ++mi)
      aB[mi] = *(const bf16x8*)(Ab + aBase + (4 + mi) * 1024);
    if (more) stageB(kt + 1, 0);
    asm volatile("" ::: "memory");
    __builtin_amdgcn_s_barrier();
    __builtin_amdgcn_s_setprio(1);
#pragma unroll
    for (int mi = 0; mi < 4; ++mi)
#pragma unroll
      for (int ni = 0; ni < 4; ++ni)
        acc[mi + 4][ni] = __builtin_amdgcn_mfma_f32_16x16x32_bf16(
            aB[mi], bk[ni], acc[mi + 4][ni], 0, 0, 0);
    __builtin_amdgcn_s_setprio(0);
    if (more) { asm volatile("s_waitcnt vmcnt(4)" ::: "memory"); }
    else      { asm volatile("s_waitcnt vmcnt(0)" ::: "memory"); }
    __builtin_amdgcn_s_barrier();
#pragma unroll
    for (int ni = 0; ni < 4; ++ni)
      bk[ni] = *(const bf16x8*)(Bb + 16384 + bBase + ni * 1024);
#pragma unroll
    for (int mi = 0; mi < 4; ++mi)
      aA[mi] = *(const bf16x8*)(Ab + 16384 + aBase + mi * 1024);
    if (more) stageA(kt + 1, 1);
    asm volatile("" ::: "memory");
    __builtin_amdgcn_s_barrier();
    __builtin_amdgcn_s_setprio(1);
#pragma unroll
    for (int mi = 0; mi < 4; ++mi)
#pragma unroll
      for (int ni = 0; ni < 4; ++ni)
        acc[mi][ni] = __builtin_amdgcn_mfma_f32_16x16x32_bf16(
            aA[mi], bk[ni], acc[mi][ni], 0, 0, 0);
    __builtin_amdgcn_s_setprio(0);
    asm volatile("" ::: "memory");
    __builtin_amdgcn_s_barrier();
#pragma unroll
    for (int mi = 0; mi < 4; ++mi)
      aB[mi] = *(const bf16x8*)(Ab + 16384 + aBase + (4 + mi) * 1024);
    if (more) stageB(kt + 1, 1);
    asm volatile("" ::: "memory");
    __builtin_amdgcn_s_barrier();
    __builtin_amdgcn_s_setprio(1);
#pragma unroll
    for (int mi = 0; mi < 4; ++mi)
#pragma unroll
      for (int ni = 0; ni < 4; ++ni)
        acc[mi + 4][ni] = __builtin_amdgcn_mfma_f32_16x16x32_bf16(
            aB[mi], bk[ni], acc[mi + 4][ni], 0, 0, 0);
    __builtin_amdgcn_s_setprio(0);
    if (more) { asm volatile("s_waitcnt vmcnt(4)" ::: "memory"); }
    __builtin_amdgcn_s_barrier();
  }
}

// ---------------------------------------------------------------------------
// Fused encoder + partial Wdec transpose (r12, unchanged).
// ---------------------------------------------------------------------------
__global__ __launch_bounds__(512, 2) void enc_fused(
    const unsigned short* __restrict__ sxT,   // (L,B,A)
    const unsigned short* __restrict__ wT,    // (L,F,A)
    const float* __restrict__ theta,          // (L,F)
    float* __restrict__ enc_out,              // (B,L,F)
    unsigned short* __restrict__ act,         // (L,B,F)
    const float* __restrict__ wdec_in,        // (NTRI,F,A) f32
    unsigned short* __restrict__ wdecT_out)   // (NTRI,A,F) bf16
{
  extern __shared__ __align__(16) char lds[];
  const int bidx = blockIdx.x;
  const int grp = bidx / 17;
  const int rem = bidx - grp * 17;

  if (rem >= 8) {
    const int tr = grp * 9 + (rem - 8);     // 0..3455
    const int y = tr & 63;
    const int z = 24 + (tr >> 6);           // 24..77
    float (*tile)[65] = (float(*)[65])lds;
    const float* inz = wdec_in + (size_t)z * F_ * A_;
    unsigned short* outz = wdecT_out + (size_t)z * F_ * A_;
    const int r0 = y * 64;
    const int t = threadIdx.x;
    for (int xq = 0; xq < 12; ++xq) {
      const int c0 = xq * 64;
      {
        const int c = (t & 15) * 4;
        const int rb = t >> 4;
#pragma unroll
        for (int q = 0; q < 2; ++q) {
          const int r = rb + q * 32;
          float4 v = *(const float4*)(inz + (size_t)(r0 + r) * A_ + (c0 + c));
          tile[r][c] = v.x; tile[r][c + 1] = v.y;
          tile[r][c + 2] = v.z; tile[r][c + 3] = v.w;
        }
      }
      __syncthreads();
      {
        const int c = t >> 3;
        const int rb8 = (t & 7) * 8;
        u16x8 o;
#pragma unroll
        for (int j = 0; j < 8; ++j) o[j] = f32_to_bf16(tile[rb8 + j][c]);
        *(u16x8*)(outz + (size_t)(c0 + c) * F_ + (r0 + rb8)) = o;
      }
      __syncthreads();
    }
    return;
  }

  char* AS = lds;
  char* BS = lds + 65536;
  const int e = grp * 8 + rem;
  const int wg = (e & 7) * 384 + (e >> 3);
  const int l = wg >> 8;
  const int blk = wg & 255;
  const int m0 = (blk & 15) * 256;
  const int n0 = (blk >> 4) * 256;
  const int tid = threadIdx.x;
  const int w = tid >> 6, lane = tid & 63;
  const int wr = w >> 2, wc = w & 3;
  const int srowS = w * 16 + (lane >> 2);
  const int chnkS = ((lane & 3) ^ ((lane >> 3) & 3)) * 16;

  const char* gA0s = (const char*)sxT +
      ((size_t)l * B_ + m0 + srowS) * (A_ * 2) + chnkS;
  const char* gB0s = (const char*)wT +
      ((size_t)l * F_ + n0 + srowS) * (A_ * 2) + chnkS;

  f32x4 acc[8][4] = {};
  auto koffA = [](int kt) { return (uint32_t)kt * 128u; };
  auto koffB = [](int kt) { return (uint32_t)kt * 128u; };
  gemm_core64(A_ / 64, AS, BS, gA0s, gB0s, A_ * 2, A_ * 2, w, wr, wc, lane,
              koffA, koffB, acc);

  const int g = lane >> 4, fr = lane & 15;
#pragma unroll
  for (int ni = 0; ni < 4; ++ni) {
    const int gcol = n0 + wc * 64 + ni * 16 + fr;
    const float th = theta[(size_t)l * F_ + gcol];
#pragma unroll
    for (int mi = 0; mi < 8; ++mi) {
      const int growb = m0 + wr * 128 + mi * 16 + g * 4;
#pragma unroll
      for (int jj = 0; jj < 4; ++jj) {
        const float v = acc[mi][ni][jj];
        const size_t grow = (size_t)(growb + jj);
        enc_out[(grow * L_ + l) * F_ + gcol] = v;
        act[((size_t)l * B_ + grow) * F_ + gcol] =
            (v > th) ? f32_to_bf16(v) : (unsigned short)0;
      }
    }
  }
}

// ---------------------------------------------------------------------------
// Decoder (r11 core) with r2's work-balanced XCD-chunked mapping:
// XCD x (= b%8 under round-robin dispatch) gets blocks x*6..x*6+5 of EVERY
// layer (equal work per XCD), heavy layers first within each XCD; blocks on
// one XCD share n0 runs -> partial B-panel L2 locality.
// ---------------------------------------------------------------------------
__global__ __launch_bounds__(512, 2) void dec_gemm8(
    const unsigned short* __restrict__ act,    // (L,B,F)
    const unsigned short* __restrict__ wdecT,  // (NTRI,A,F)
    float* __restrict__ logits)                // (B,L,A)
{
  extern __shared__ __align__(16) char lds[];
  char* AS = lds;
  char* BS = lds + 65536;
  const int b = blockIdx.x;
  const int xcd = b & 7;
  const int idx = b >> 3;          // 0..71
  const int z = idx / 6;           // 0..11, heavy first
  const int j = idx - z * 6;
  const int i = 11 - z;
  const int blk = xcd * 6 + j;     // 0..47
  const int m0 = (blk & 15) * 256;
  const int n0 = (blk >> 4) * 256; // {0,256,512}
  const int triBase = i * (i + 1) / 2;
  const int KT = (i + 1) * 64;     // BK=64 tiles
  const int tid = threadIdx.x;
  const int w = tid >> 6, lane = tid & 63;
  const int wr = w >> 2, wc = w & 3;
  const int srowS = w * 16 + (lane >> 2);
  const int chnkS = ((lane & 3) ^ ((lane >> 3) & 3)) * 16;

  const char* gA0s =
      (const char*)act + ((size_t)(m0 + srowS)) * (F_ * 2) + chnkS;
  const char* gB0s = (const char*)wdecT +
      ((size_t)(triBase * A_ + n0 + srowS)) * (F_ * 2) + chnkS;

  f32x4 acc[8][4] = {};
  auto koffA = [](int kt) {
    return (uint32_t)(kt >> 6) * (uint32_t)(B_ * F_ * 2) +
           (uint32_t)(kt & 63) * 128u;
  };
  auto koffB = [](int kt) {
    return (uint32_t)(kt >> 6) * (uint32_t)(A_ * F_ * 2) +
           (uint32_t)(kt & 63) * 128u;
  };
  gemm_core64(KT, AS, BS, gA0s, gB0s, F_ * 2, F_ * 2, w, wr, wc, lane,
              koffA, koffB, acc);

  const int g = lane >> 4, fr = lane & 15;
#pragma unroll
  for (int mi = 0; mi < 8; ++mi) {
    const int growb = m0 + wr * 128 + mi * 16 + g * 4;
#pragma unroll
    for (int ni = 0; ni < 4; ++ni) {
      const int gcol = n0 + wc * 64 + ni * 16 + fr;
#pragma unroll
      for (int jj = 0; jj < 4; ++jj)
        logits[((size_t)(growb + jj) * L_ + i) * A_ + gcol] = acc[mi][ni][jj];
    }
  }
}

// ---------------------------------------------------------------------------
extern "C" void kernel_launch(void* const* d_in, const int* in_sizes, int n_in,
                              void* d_out, int out_size, void* d_ws,
                              size_t ws_size, hipStream_t stream) {
  (void)in_sizes; (void)n_in; (void)out_size; (void)ws_size;
  const float* x = (const float*)d_in[0];
  const float* mean = (const float*)d_in[1];
  const float* stdv = (const float*)d_in[2];
  const float* Wenc = (const float*)d_in[3];
  const float* theta = (const float*)d_in[4];
  const float* Wdec = (const float*)d_in[5];

  float* logits = (float*)d_out;
  float* enc = (float*)d_out + (size_t)B_ * L_ * A_;

  char* ws = (char*)d_ws;
  const size_t actBytes = (size_t)L_ * B_ * F_ * 2;      // 402.7 MB
  const size_t sxBytes = (size_t)L_ * B_ * A_ * 2;       // 75.5 MB
  unsigned short* act = (unsigned short*)ws;
  unsigned short* sx = (unsigned short*)(ws + actBytes);
  unsigned short* wencT = (unsigned short*)(ws + actBytes + sxBytes);
  // wdecT aliases over sx+wencT; tris >=24 lie beyond them (safe during enc).
  unsigned short* wdecT = (unsigned short*)(ws + actBytes);

  hipFuncSetAttribute((const void*)enc_fused,
                      hipFuncAttributeMaxDynamicSharedMemorySize, 131072);
  hipFuncSetAttribute((const void*)dec_gemm8,
                      hipFuncAttributeMaxDynamicSharedMemorySize, 131072);

  // prep_sx (36864 blocks) + Wenc transpose (9216 blocks) fused:
  prep_enc_inputs<<<46080, 256, 0, stream>>>(x, mean, stdv, sx, Wenc, wencT);
  enc_fused<<<6528, 512, 131072, stream>>>(sx, wencT, theta, enc, act,
                                           Wdec, wdecT);
  transpose_cvt64<<<dim3(A_ / 64, F_ / 64, 24), 256, 0, stream>>>(
      Wdec, wdecT, F_, A_);
  dec_gemm8<<<576, 512, 131072, stream>>>(act, wdecT, logits);
}